// Round 3
// baseline (431.450 us; speedup 1.0000x reference)
//
#include <hip/hip_runtime.h>
#include <cstddef>

// ---------------------------------------------------------------------------
// Fused equivariant decoder, MI355X (gfx950) — round 3.
// Phase 1: scalar (l=0) chain cooperatively, 4 barriers, publishes gate
//   vectors G1,G2,G3 to LDS.
// Phase 2: ZERO barriers. 27 (chain l, c-tile) units statically assigned to
//   the 4 waves; each unit (stage -> L1 -> L2 -> L3 -> dot) is wave-private:
//   cross-lane LDS dependencies are resolved with in-order DS + an
//   s_waitcnt lgkmcnt(0) fence (no __syncthreads). Next unit's global loads
//   are register-prefetched one unit ahead.
// Weights pre-packed as A-operand MFMA fragments (W^T/sqrt(K)) in d_ws.
// ---------------------------------------------------------------------------

typedef _Float16 half8 __attribute__((ext_vector_type(8)));
typedef _Float16 half4 __attribute__((ext_vector_type(4)));
typedef float    f32x4 __attribute__((ext_vector_type(4)));
typedef float    fvec4 __attribute__((ext_vector_type(4)));

#define B_ROWS   8
#define IN_DIM   3840
#define OUT_COLS 49

// LDS layout (in _Float16 elements); all row pitches keep 16B alignment.
#define OFF_STG0 0            // 16*264 = 4224   (l0 staging, rows 8..15 garbage)
#define OFF_HSA  4224         // 16*72  = 1152
#define OFF_HSB  5376         // 1152
#define OFF_G1   6528         // 8*264  = 2112
#define OFF_G2   8640         // 2112
#define OFF_G3   10752        // 2112
#define OFF_SW   12864        // 4 * (16*136) = 8704   per-wave staging arena
#define OFF_H1   21568        // 4 * (16*72)  = 4608   per-wave H scratch
#define SMEM_ELTS 26176       // *2B = 52352 B -> 3 blocks/CU

#define P2BASE 106496
#define P3BASE 139264

// wave-internal LDS fence: DS ops complete in order per wave; this waits for
// them and (memory clobber) stops the compiler reordering across it.
__device__ __forceinline__ void wave_fence() {
  asm volatile("s_waitcnt lgkmcnt(0)" ::: "memory");
}

// ---------------------------------------------------------------------------
// Weight prep (same packing as R2; consumed as A-fragments).
// ---------------------------------------------------------------------------
__global__ __launch_bounds__(256) void prep_weights(
    const float* __restrict__ w1, const float* __restrict__ w2,
    const float* __restrict__ w3, _Float16* __restrict__ packed)
{
  static const int K_[24]    = {256,256,128,128,64,64,64,64,  64,64,64,64,32,32,32,32,
                                64,64,64,64,32,32,32,32};
  static const int N_[24]    = {64,256,64,64,32,32,32,32,  64,256,64,64,32,32,32,32,
                                64,256,64,64,32,32,32,32};
  static const int woff_[24] = {0,16384,81920,90112,98304,100352,102400,104448,
                                0,4096,20480,24576,28672,29696,30720,31744,
                                0,4096,20480,24576,28672,29696,30720,31744};
  static const int poff_[24] = {0,16384,81920,90112,98304,100352,102400,104448,
                                106496,110592,126976,131072,135168,136192,137216,138240,
                                139264,143360,159744,163840,167936,168960,169984,171008};
  const int g = blockIdx.x * 256 + threadIdx.x;   // 0 .. 21503
  int bi = 0;
#pragma unroll
  for (int i = 1; i < 24; ++i) if (g * 8 >= poff_[i]) bi = i;
  const float* w = (bi < 8) ? w1 : ((bi < 16) ? w2 : w3);
  const int rel8 = g - poff_[bi] / 8;
  const int lane = rel8 & 63;
  const int fi   = rel8 >> 6;
  const int K = K_[bi], N = N_[bi];
  const int KF = K >> 5;
  const int kf = fi % KF;
  const int mt = fi / KF;
  const int k0 = kf * 32 + (lane >> 4) * 8;
  const int o  = mt * 16 + (lane & 15);
  const float scale = 1.0f / sqrtf((float)K);
  half8 vv;
#pragma unroll
  for (int j = 0; j < 8; ++j)
    vv[j] = (_Float16)(w[woff_[bi] + (size_t)(k0 + j) * N + o] * scale);
  *(half8*)(packed + (size_t)g * 8) = vv;
}

// ---------------------------------------------------------------------------
// Per-chain compile-time parameters.
// ---------------------------------------------------------------------------
template<int L> struct CP {
  static constexpr int TWOL1 = 2 * L + 1;
  static constexpr int MUL   = (L <= 2) ? 128 : 64;   // layer-1 K
  static constexpr int N1    = (L <= 2) ? 64  : 32;   // hidden mul
  static constexpr int KF1   = MUL / 32;
  static constexpr int KF2   = N1 / 32;               // 2 or 1
  static constexpr int MT    = N1 / 16;               // 4 or 2
  static constexpr int AP    = MUL + 8;               // staging pitch
  static constexpr int HP    = N1 + 8;                // hidden pitch
  static constexpr int R     = 8 * TWOL1;
  static constexpr int NQ    = (16 * (MUL / 4)) / 64; // 8 or 4 load iters
  static constexpr int INOFF = (L==1)?256:(L==2)?640:(L==3)?1280:(L==4)?1728:(L==5)?2304:3008;
  static constexpr int P1    = (L==1)?81920:(L==2)?90112:(L==3)?98304:(L==4)?100352:(L==5)?102400:104448;
  static constexpr int P2R   = (L==1)?20480:(L==2)?24576:(L==3)?28672:(L==4)?29696:(L==5)?30720:31744;
  static constexpr int GO    = (L==1)?0:(L==2)?64:(L==3)?128:(L==4)?160:(L==5)?192:224;
  static constexpr int W4O   = (L==1)?64:(L==2)?128:(L==3)?192:(L==4)?224:(L==5)?256:288;
};

// Global -> register loads for one unit (issued one unit ahead).
// lane element (cc=flat&15, iq=flat>>4): 4 dwords X[b(c)][ (iq*4+jj)*TWOL1 + m(c) ].
template<int L, int CT>
__device__ __forceinline__ void unit_load(const float* __restrict__ vraw,
                                          int b0, float (&rg)[32])
{
  using P = CP<L>;
  const int lane = threadIdx.x & 63;
#pragma unroll
  for (int v = 0; v < P::NQ; ++v) {
    const int flat = v * 64 + lane;
    const int cc = flat & 15;
    const int iq = flat >> 4;
    const int c  = CT * 16 + cc;
    if (c < P::R) {
      const int b = c / P::TWOL1;
      const int m = c - b * P::TWOL1;
      const float* base = vraw + (size_t)(b0 + b) * IN_DIM + P::INOFF + m
                        + (size_t)(iq * 4) * P::TWOL1;
#pragma unroll
      for (int jj = 0; jj < 4; ++jj) rg[v * 4 + jj] = base[(size_t)jj * P::TWOL1];
    }
  }
}

// Register -> LDS staging: half4 writes, row cc, pitch AP (2-way max banks).
template<int L, int CT>
__device__ __forceinline__ void unit_stage(const float (&rg)[32], _Float16* SW)
{
  using P = CP<L>;
  const int lane = threadIdx.x & 63;
#pragma unroll
  for (int v = 0; v < P::NQ; ++v) {
    const int flat = v * 64 + lane;
    const int cc = flat & 15;
    const int iq = flat >> 4;
    if (CT * 16 + cc < P::R) {
      half4 h;
#pragma unroll
      for (int jj = 0; jj < 4; ++jj) h[jj] = (_Float16)rg[v * 4 + jj];
      *(half4*)(SW + cc * P::AP + iq * 4) = h;
    }
  }
}

// One full unit: L1 (gate G1) -> L2 (G2) -> L3 (G3) -> w4 dot -> out.
// All LDS traffic wave-private. MFMA C layout: rows o = mt*16+quad*4+r,
// col = c-tile column (lane&15).
template<int L, int CT>
__device__ __forceinline__ void unit_compute(
    _Float16* SW, _Float16* H1, const _Float16* __restrict__ pk,
    const _Float16* G1, const _Float16* G2, const _Float16* G3,
    const float* __restrict__ w4, float* __restrict__ out, int b0)
{
  using P = CP<L>;
  const int lane = threadIdx.x & 63;
  const int col  = lane & 15;
  const int quad = lane >> 4;
  const int c    = CT * 16 + col;
  const bool vc  = c < P::R;
  const int b    = c / P::TWOL1;
  const int m    = c - b * P::TWOL1;
  // L1: K=MUL, B-frags from SW (pitch AP)
#pragma unroll
  for (int mt = 0; mt < P::MT; ++mt) {
    f32x4 acc = {0.f, 0.f, 0.f, 0.f};
#pragma unroll
    for (int kf = 0; kf < P::KF1; ++kf) {
      const half8 av = *(const half8*)(pk + P::P1 + (size_t)((mt * P::KF1 + kf) * 64 + lane) * 8);
      const half8 bv = *(const half8*)(SW + col * P::AP + kf * 32 + quad * 8);
      acc = __builtin_amdgcn_mfma_f32_16x16x32_f16(av, bv, acc, 0, 0, 0);
    }
    if (vc) {
      const int o0 = mt * 16 + quad * 4;
      const half4 g4 = *(const half4*)(G1 + b * 264 + P::GO + o0);
      half4 hv;
#pragma unroll
      for (int r = 0; r < 4; ++r) hv[r] = (_Float16)(acc[r] * (float)g4[r]);
      *(half4*)(H1 + col * P::HP + o0) = hv;
    }
  }
  wave_fence();
  // L2: K=N1, B=H1 (pitch HP) -> SW (pitch HP, staging fully consumed)
#pragma unroll
  for (int mt = 0; mt < P::MT; ++mt) {
    f32x4 acc = {0.f, 0.f, 0.f, 0.f};
#pragma unroll
    for (int kf = 0; kf < P::KF2; ++kf) {
      const half8 av = *(const half8*)(pk + P2BASE + P::P2R + (size_t)((mt * P::KF2 + kf) * 64 + lane) * 8);
      const half8 bv = *(const half8*)(H1 + col * P::HP + kf * 32 + quad * 8);
      acc = __builtin_amdgcn_mfma_f32_16x16x32_f16(av, bv, acc, 0, 0, 0);
    }
    if (vc) {
      const int o0 = mt * 16 + quad * 4;
      const half4 g4 = *(const half4*)(G2 + b * 264 + P::GO + o0);
      half4 hv;
#pragma unroll
      for (int r = 0; r < 4; ++r) hv[r] = (_Float16)(acc[r] * (float)g4[r]);
      *(half4*)(SW + col * P::HP + o0) = hv;
    }
  }
  wave_fence();
  // L3: B=SW (pitch HP) -> H1
#pragma unroll
  for (int mt = 0; mt < P::MT; ++mt) {
    f32x4 acc = {0.f, 0.f, 0.f, 0.f};
#pragma unroll
    for (int kf = 0; kf < P::KF2; ++kf) {
      const half8 av = *(const half8*)(pk + P3BASE + P::P2R + (size_t)((mt * P::KF2 + kf) * 64 + lane) * 8);
      const half8 bv = *(const half8*)(SW + col * P::HP + kf * 32 + quad * 8);
      acc = __builtin_amdgcn_mfma_f32_16x16x32_f16(av, bv, acc, 0, 0, 0);
    }
    if (vc) {
      const int o0 = mt * 16 + quad * 4;
      const half4 g4 = *(const half4*)(G3 + b * 264 + P::GO + o0);
      half4 hv;
#pragma unroll
      for (int r = 0; r < 4; ++r) hv[r] = (_Float16)(acc[r] * (float)g4[r]);
      *(half4*)(H1 + col * P::HP + o0) = hv;
    }
  }
  wave_fence();
  // dot with w4: each quad covers N1/4 of K; reduce across quads via shuffles.
  float s = 0.f;
  if (vc) {
    constexpr int SEG = P::N1 / 4;
#pragma unroll
    for (int h8 = 0; h8 < SEG / 8; ++h8) {
      const half8 hv = *(const half8*)(H1 + col * P::HP + quad * SEG + h8 * 8);
#pragma unroll
      for (int j = 0; j < 8; ++j)
        s += (float)hv[j] * w4[P::W4O + quad * SEG + h8 * 8 + j];
    }
  }
  s += __shfl_xor(s, 16, 64);
  s += __shfl_xor(s, 32, 64);
  if (vc && quad == 0) {
    constexpr float scale = (P::N1 == 64) ? 0.125f : 0.17677669529663687f;
    out[(size_t)(b0 + b) * OUT_COLS + L * L + m] = s * scale;
  }
}

// ---------------------------------------------------------------------------
// Scalar (l=0) chain, cooperative (from R2).
// ---------------------------------------------------------------------------
__device__ __forceinline__ void ws_l0(const fvec4 (&regs)[2], _Float16* stg)
{
  const int t = threadIdx.x;
#pragma unroll
  for (int v = 0; v < 2; ++v) {
    const int gv = v * 256 + t;       // < 512
    const int b  = gv >> 6;
    const int i0 = (gv & 63) * 4;
    const fvec4 x = regs[v];
    half4 h;
#pragma unroll
    for (int j = 0; j < 4; ++j) h[j] = (_Float16)x[j];
    *(half4*)(stg + b * 264 + i0) = h;
  }
}

template<int K>
__device__ __forceinline__ void scal_sw(
    const _Float16* __restrict__ Bact, const _Float16* __restrict__ ApS,
    const _Float16* __restrict__ ApG, _Float16* __restrict__ HsOut,
    _Float16* __restrict__ Gout, int AP_)
{
  constexpr int KF = K / 32;
  const int lane = threadIdx.x & 63;
  const int wave = threadIdx.x >> 6;
  const int col  = lane & 15;
  const int quad = lane >> 4;
  const _Float16* bp = Bact + col * AP_ + quad * 8;
  {                                    // silu part: 4 tiles, one per wave
    const int mt = wave;
    f32x4 acc = {0.f, 0.f, 0.f, 0.f};
    const _Float16* ap = ApS + ((size_t)(mt * KF * 64 + lane)) * 8;
#pragma unroll
    for (int kf = 0; kf < KF; ++kf)
      acc = __builtin_amdgcn_mfma_f32_16x16x32_f16(
          *(const half8*)(ap + kf * 512), *(const half8*)(bp + kf * 32), acc, 0, 0, 0);
    if (col < B_ROWS) {
      const int o0 = mt * 16 + quad * 4;
      half4 hv;
#pragma unroll
      for (int r = 0; r < 4; ++r) {
        const float z = acc[r];
        hv[r] = (_Float16)(z / (1.f + __expf(-z)));
      }
      *(half4*)(HsOut + col * 72 + o0) = hv;
    }
  }
#pragma unroll
  for (int mt0 = 0; mt0 < 4; ++mt0) {  // gate part: 16 tiles
    const int mt = mt0 * 4 + wave;
    f32x4 acc = {0.f, 0.f, 0.f, 0.f};
    const _Float16* ap = ApG + ((size_t)(mt * KF * 64 + lane)) * 8;
#pragma unroll
    for (int kf = 0; kf < KF; ++kf)
      acc = __builtin_amdgcn_mfma_f32_16x16x32_f16(
          *(const half8*)(ap + kf * 512), *(const half8*)(bp + kf * 32), acc, 0, 0, 0);
    if (col < B_ROWS) {
      const int o0 = mt * 16 + quad * 4;
      half4 gv;
#pragma unroll
      for (int r = 0; r < 4; ++r)
        gv[r] = (_Float16)(1.f / (1.f + __expf(-acc[r])));
      *(half4*)(Gout + col * 264 + o0) = gv;
    }
  }
}

__device__ __forceinline__ void scalar_dot(const _Float16* __restrict__ Hs,
                                           const float* __restrict__ w4,
                                           float* __restrict__ out, int b0)
{
  const int r = threadIdx.x;           // wave 0 lanes 0..7
  if (r < B_ROWS) {
    float s = 0.f;
#pragma unroll
    for (int i8 = 0; i8 < 8; ++i8) {
      const half8 hv = *(const half8*)(Hs + r * 72 + i8 * 8);
#pragma unroll
      for (int j = 0; j < 8; ++j) s += (float)hv[j] * w4[i8 * 8 + j];
    }
    out[(size_t)(b0 + r) * OUT_COLS] = s * 0.125f;
  }
}

// ---------------------------------------------------------------------------
// Main kernel.
// ---------------------------------------------------------------------------
__global__ __launch_bounds__(256, 3) void fused_decoder(
    const float* __restrict__ vraw, const float* __restrict__ w4,
    const _Float16* __restrict__ pk, float* __restrict__ out)
{
  __shared__ __align__(16) _Float16 smem[SMEM_ELTS];
  _Float16* STG0 = smem + OFF_STG0;
  _Float16* HsA  = smem + OFF_HSA;
  _Float16* HsB  = smem + OFF_HSB;
  _Float16* G1   = smem + OFF_G1;
  _Float16* G2   = smem + OFF_G2;
  _Float16* G3   = smem + OFF_G3;
  const int wv = threadIdx.x >> 6;
  _Float16* SW = smem + OFF_SW + wv * 2176;   // 16 x 136 arena
  _Float16* H1 = smem + OFF_H1 + wv * 1152;   // 16 x 72 arena
  const int b0 = blockIdx.x * B_ROWS;

  // ---- issue global loads: l0 staging + each wave's first unit ----
  fvec4 rA[2];
  {
    const int t = threadIdx.x;
#pragma unroll
    for (int v = 0; v < 2; ++v) {
      const int gv = v * 256 + t;
      rA[v] = *(const fvec4*)(vraw + (size_t)(b0 + (gv >> 6)) * IN_DIM + (gv & 63) * 4);
    }
  }
  float rg[32];
  if      (wv == 0) unit_load<2,0>(vraw, b0, rg);
  else if (wv == 1) unit_load<1,0>(vraw, b0, rg);
  else if (wv == 2) unit_load<6,0>(vraw, b0, rg);
  else              unit_load<5,0>(vraw, b0, rg);

  // ---- phase 1: scalar chain (4 barriers) ----
  ws_l0(rA, STG0);
  __syncthreads();
  scal_sw<256>(STG0, pk + 0, pk + 16384, HsA, G1, 264);
  __syncthreads();
  scal_sw<64>(HsA, pk + P2BASE, pk + P2BASE + 4096, HsB, G2, 72);
  __syncthreads();
  scal_sw<64>(HsB, pk + P3BASE, pk + P3BASE + 4096, HsA, G3, 72);
  __syncthreads();

  // ---- phase 2: barrier-free per-wave unit streams ----
#define RUN_PF(Lc, CTc, Ln, CTn)                                   \
  unit_stage<Lc, CTc>(rg, SW); wave_fence();                       \
  unit_load<Ln, CTn>(vraw, b0, rg);                                \
  unit_compute<Lc, CTc>(SW, H1, pk, G1, G2, G3, w4, out, b0);
#define RUN_LAST(Lc, CTc)                                          \
  unit_stage<Lc, CTc>(rg, SW); wave_fence();                       \
  unit_compute<Lc, CTc>(SW, H1, pk, G1, G2, G3, w4, out, b0);

  if (wv == 0) {
    scalar_dot(HsA, w4, out, b0);
    RUN_PF(2,0, 2,1); RUN_PF(2,1, 2,2); RUN_PF(2,2, 3,3);
    RUN_LAST(3,3);
  } else if (wv == 1) {
    RUN_PF(1,0, 1,1); RUN_PF(1,1, 4,0); RUN_PF(4,0, 4,1);
    RUN_PF(4,1, 4,2); RUN_LAST(4,2);
  } else if (wv == 2) {
    RUN_PF(6,0, 6,1); RUN_PF(6,1, 6,2); RUN_PF(6,2, 6,3);
    RUN_PF(6,3, 6,4); RUN_PF(6,4, 6,5); RUN_PF(6,5, 6,6);
    RUN_PF(6,6, 3,0); RUN_PF(3,0, 3,1); RUN_LAST(3,1);
  } else {
    RUN_PF(5,0, 5,1); RUN_PF(5,1, 5,2); RUN_PF(5,2, 5,3);
    RUN_PF(5,3, 5,4); RUN_PF(5,4, 5,5); RUN_PF(5,5, 4,3);
    RUN_PF(4,3, 4,4); RUN_PF(4,4, 3,2); RUN_LAST(3,2);
  }
#undef RUN_PF
#undef RUN_LAST
}

extern "C" void kernel_launch(void* const* d_in, const int* in_sizes, int n_in,
                              void* d_out, int out_size, void* d_ws, size_t ws_size,
                              hipStream_t stream)
{
  (void)in_sizes; (void)n_in; (void)out_size; (void)ws_size;
  const float* vraw = (const float*)d_in[0];
  const float* w1   = (const float*)d_in[1];
  const float* w2   = (const float*)d_in[2];
  const float* w3   = (const float*)d_in[3];
  const float* w4   = (const float*)d_in[4];
  float* out = (float*)d_out;
  _Float16* packed = (_Float16*)d_ws;   // 172032 elems = 344064 B

  prep_weights<<<84, 256, 0, stream>>>(w1, w2, w3, packed);
  fused_decoder<<<16384 / B_ROWS, 256, 0, stream>>>(vraw, w4, packed, out);
}

// Round 4
// 374.876 us; speedup vs baseline: 1.1509x; 1.1509x over previous
//
#include <hip/hip_runtime.h>
#include <cstddef>

// ---------------------------------------------------------------------------
// Fused equivariant decoder, MI355X (gfx950) — round 4.
// B_ROWS=16 (all MFMA tiles full). 3 barriers total:
//   W0: scalar L1 (B-frags direct from global) -> Hs1, G1
//   W1: scalar L2 -> Hs2, G2
//   W2: scalar L3 -> G3 + folded scalar w4-dot
//   phase 2 (no barriers): 48 (chain,c-tile) units across 4 waves; L1 B-frags
//   direct from global (strided dwords), H via wave-private LDS scratch with
//   NO fences (in-order DS per wave), w4-dot folded into L3 epilogue in regs.
// Weights pre-packed as A-operand fragments (W^T/sqrt(K)) in d_ws.
// ---------------------------------------------------------------------------

typedef _Float16 half8 __attribute__((ext_vector_type(8)));
typedef _Float16 half4 __attribute__((ext_vector_type(4)));
typedef float    f32x4 __attribute__((ext_vector_type(4)));
typedef float    fvec4 __attribute__((ext_vector_type(4)));

#define B_ROWS   16
#define IN_DIM   3840
#define OUT_COLS 49
#define GP  264           // gate row pitch (256 used)
#define HSP 72            // scalar-hidden / scratch row pitch (64 used)

// LDS map (elements of _Float16); bases all 16B-aligned.
#define OFF_G1  0         // 16*264 = 4224
#define OFF_G2  4224
#define OFF_G3  8448
#define OFF_HS1 12672     // 16*72 = 1152
#define OFF_HS2 13824
#define OFF_SCR 14976     // + wave*2304 (HSa 1152 + HSb 1152)
#define SMEM_ELTS 24192   // *2B = 48384 B

#define P2BASE 106496
#define P3BASE 139264

// ---------------------------------------------------------------------------
// Weight prep (same packed layout as R2/R3; consumed as A-fragments).
// Frag f=(mt*KF+kf)*64+lane holds W[i][o]*scale, i=kf*32+(lane>>4)*8+j,
// o=mt*16+(lane&15).
// ---------------------------------------------------------------------------
__global__ __launch_bounds__(256) void prep_weights(
    const float* __restrict__ w1, const float* __restrict__ w2,
    const float* __restrict__ w3, _Float16* __restrict__ packed)
{
  static const int K_[24]    = {256,256,128,128,64,64,64,64,  64,64,64,64,32,32,32,32,
                                64,64,64,64,32,32,32,32};
  static const int N_[24]    = {64,256,64,64,32,32,32,32,  64,256,64,64,32,32,32,32,
                                64,256,64,64,32,32,32,32};
  static const int woff_[24] = {0,16384,81920,90112,98304,100352,102400,104448,
                                0,4096,20480,24576,28672,29696,30720,31744,
                                0,4096,20480,24576,28672,29696,30720,31744};
  static const int poff_[24] = {0,16384,81920,90112,98304,100352,102400,104448,
                                106496,110592,126976,131072,135168,136192,137216,138240,
                                139264,143360,159744,163840,167936,168960,169984,171008};
  const int g = blockIdx.x * 256 + threadIdx.x;   // 0 .. 21503
  int bi = 0;
#pragma unroll
  for (int i = 1; i < 24; ++i) if (g * 8 >= poff_[i]) bi = i;
  const float* w = (bi < 8) ? w1 : ((bi < 16) ? w2 : w3);
  const int rel8 = g - poff_[bi] / 8;
  const int lane = rel8 & 63;
  const int fi   = rel8 >> 6;
  const int K = K_[bi], N = N_[bi];
  const int KF = K >> 5;
  const int kf = fi % KF;
  const int mt = fi / KF;
  const int k0 = kf * 32 + (lane >> 4) * 8;
  const int o  = mt * 16 + (lane & 15);
  const float scale = 1.0f / sqrtf((float)K);
  half8 vv;
#pragma unroll
  for (int j = 0; j < 8; ++j)
    vv[j] = (_Float16)(w[woff_[bi] + (size_t)(k0 + j) * N + o] * scale);
  *(half8*)(packed + (size_t)g * 8) = vv;
}

// ---------------------------------------------------------------------------
// Per-chain compile-time parameters.
// ---------------------------------------------------------------------------
template<int L> struct CP {
  static constexpr int TWOL1 = 2 * L + 1;
  static constexpr int K1  = (L <= 2) ? 128 : 64;
  static constexpr int N1  = (L <= 2) ? 64  : 32;
  static constexpr int KF1 = K1 / 32;
  static constexpr int KF2 = N1 / 32;
  static constexpr int MT  = N1 / 16;
  static constexpr int INOFF = (L==1)?256:(L==2)?640:(L==3)?1280:(L==4)?1728:(L==5)?2304:3008;
  static constexpr int P1    = (L==1)?81920:(L==2)?90112:(L==3)?98304:(L==4)?100352:(L==5)?102400:104448;
  static constexpr int P2R   = (L==1)?20480:(L==2)?24576:(L==3)?28672:(L==4)?29696:(L==5)?30720:31744;
  static constexpr int GO    = (L==1)?0:(L==2)?64:(L==3)?128:(L==4)?160:(L==5)?192:224;
  static constexpr int W4O   = (L==1)?64:(L==2)?128:(L==3)?192:(L==4)?224:(L==5)?256:288;
  static constexpr float SCALE = (N1 == 64) ? 0.125f : 0.17677669529663687f;
};

// Direct global B-frag loads for one unit: lane (col,quad) needs
// X[c][kf*32+quad*8+j] = vraw[(b0+b)*IN_DIM + INOFF + i*TWOL1 + m].
template<int L>
__device__ __forceinline__ void unit_load(const float* __restrict__ vraw,
                                          int b0, int ct, float (&rg)[CP<L>::KF1 * 8])
{
  using P = CP<L>;
  const int lane = threadIdx.x & 63;
  const int col  = lane & 15;
  const int quad = lane >> 4;
  const int c = ct * 16 + col;
  const int b = c / P::TWOL1;
  const int m = c - b * P::TWOL1;
  const float* base = vraw + (size_t)(b0 + b) * IN_DIM + P::INOFF + m
                    + (size_t)(quad * 8) * P::TWOL1;
#pragma unroll
  for (int kf = 0; kf < P::KF1; ++kf)
#pragma unroll
    for (int j = 0; j < 8; ++j)
      rg[kf * 8 + j] = base[(size_t)(kf * 32 + j) * P::TWOL1];
}

// One unit: L1(gate G1) -> L2(G2) -> L3(G3)+w4 dot. H via wave-private LDS
// scratch, no fences (in-order DS per wave; compiler preserves ds order on
// possibly-aliasing pointers). C layout: o = mt*16+quad*4+r, column = col.
template<int L>
__device__ __forceinline__ void unit_compute(
    const float (&rg)[CP<L>::KF1 * 8], const _Float16* __restrict__ pk,
    const _Float16* G1, const _Float16* G2, const _Float16* G3,
    _Float16* HSa, _Float16* HSb,
    const float* __restrict__ w4, float* __restrict__ out, int b0, int ct)
{
  using P = CP<L>;
  const int lane = threadIdx.x & 63;
  const int col  = lane & 15;
  const int quad = lane >> 4;
  const int c = ct * 16 + col;
  const int b = c / P::TWOL1;
  const int m = c - b * P::TWOL1;
  half8 bf[P::KF1];
#pragma unroll
  for (int kf = 0; kf < P::KF1; ++kf)
#pragma unroll
    for (int j = 0; j < 8; ++j) bf[kf][j] = (_Float16)rg[kf * 8 + j];
  // ---- L1 -> HSa ----
#pragma unroll
  for (int mt = 0; mt < P::MT; ++mt) {
    f32x4 acc = {0.f, 0.f, 0.f, 0.f};
#pragma unroll
    for (int kf = 0; kf < P::KF1; ++kf) {
      const half8 av = *(const half8*)(pk + P::P1 + (size_t)((mt * P::KF1 + kf) * 64 + lane) * 8);
      acc = __builtin_amdgcn_mfma_f32_16x16x32_f16(av, bf[kf], acc, 0, 0, 0);
    }
    const int o0 = mt * 16 + quad * 4;
    const half4 g4 = *(const half4*)(G1 + b * GP + P::GO + o0);
    half4 h;
#pragma unroll
    for (int r = 0; r < 4; ++r) h[r] = (_Float16)(acc[r] * (float)g4[r]);
    *(half4*)(HSa + col * HSP + o0) = h;
  }
  // ---- L2: HSa -> HSb ----
#pragma unroll
  for (int mt = 0; mt < P::MT; ++mt) {
    f32x4 acc = {0.f, 0.f, 0.f, 0.f};
#pragma unroll
    for (int kf = 0; kf < P::KF2; ++kf) {
      const half8 av = *(const half8*)(pk + P2BASE + P::P2R + (size_t)((mt * P::KF2 + kf) * 64 + lane) * 8);
      const half8 bv = *(const half8*)(HSa + col * HSP + kf * 32 + quad * 8);
      acc = __builtin_amdgcn_mfma_f32_16x16x32_f16(av, bv, acc, 0, 0, 0);
    }
    const int o0 = mt * 16 + quad * 4;
    const half4 g4 = *(const half4*)(G2 + b * GP + P::GO + o0);
    half4 h;
#pragma unroll
    for (int r = 0; r < 4; ++r) h[r] = (_Float16)(acc[r] * (float)g4[r]);
    *(half4*)(HSb + col * HSP + o0) = h;
  }
  // ---- L3 + folded w4 dot ----
  float s = 0.f;
#pragma unroll
  for (int mt = 0; mt < P::MT; ++mt) {
    f32x4 acc = {0.f, 0.f, 0.f, 0.f};
#pragma unroll
    for (int kf = 0; kf < P::KF2; ++kf) {
      const half8 av = *(const half8*)(pk + P3BASE + P::P2R + (size_t)((mt * P::KF2 + kf) * 64 + lane) * 8);
      const half8 bv = *(const half8*)(HSb + col * HSP + kf * 32 + quad * 8);
      acc = __builtin_amdgcn_mfma_f32_16x16x32_f16(av, bv, acc, 0, 0, 0);
    }
    const int o0 = mt * 16 + quad * 4;
    const half4 g4 = *(const half4*)(G3 + b * GP + P::GO + o0);
#pragma unroll
    for (int r = 0; r < 4; ++r)
      s += acc[r] * (float)g4[r] * w4[P::W4O + o0 + r];
  }
  s += __shfl_xor(s, 16, 64);
  s += __shfl_xor(s, 32, 64);
  if (quad == 0)
    out[(size_t)(b0 + b) * OUT_COLS + L * L + m] = s * P::SCALE;
}

// Chain runner: software pipeline depth 1 on the global B-loads.
template<int L, int CT0, int NCT>
__device__ __forceinline__ void run_chain(
    const float* __restrict__ vraw, const _Float16* __restrict__ pk,
    const _Float16* G1, const _Float16* G2, const _Float16* G3,
    _Float16* HSa, _Float16* HSb,
    const float* __restrict__ w4, float* __restrict__ out, int b0)
{
  float rg[2][CP<L>::KF1 * 8];
  unit_load<L>(vraw, b0, CT0, rg[0]);
#pragma unroll
  for (int u = 0; u < NCT; ++u) {
    if (u + 1 < NCT) unit_load<L>(vraw, b0, CT0 + u + 1, rg[(u + 1) & 1]);
    unit_compute<L>(rg[u & 1], pk, G1, G2, G3, HSa, HSb, w4, out, b0, CT0 + u);
  }
}

// ---------------------------------------------------------------------------
// Scalar (l=0) chain. B-frags: lane col = batch row b (16 valid of 16!).
// ---------------------------------------------------------------------------
__device__ __forceinline__ void load_scal_frags(const float* __restrict__ vraw,
                                                int b0, half8 (&sf)[8])
{
  const int lane = threadIdx.x & 63;
  const int col  = lane & 15;
  const int quad = lane >> 4;
  const float* base = vraw + (size_t)(b0 + col) * IN_DIM + quad * 8;
#pragma unroll
  for (int kf = 0; kf < 8; ++kf) {
    const fvec4 a = *(const fvec4*)(base + kf * 32);
    const fvec4 b2 = *(const fvec4*)(base + kf * 32 + 4);
#pragma unroll
    for (int j = 0; j < 4; ++j) { sf[kf][j] = (_Float16)a[j]; sf[kf][4 + j] = (_Float16)b2[j]; }
  }
}

// W0: scalar L1 (K=256). silu tile = wave; gate tiles = wave*4..+3.
__device__ __forceinline__ void scal_L1(const half8 (&sf)[8],
    const _Float16* __restrict__ pk, _Float16* Hs1, _Float16* G1v)
{
  const int lane = threadIdx.x & 63;
  const int wv   = threadIdx.x >> 6;
  const int col  = lane & 15;
  const int quad = lane >> 4;
  {
    f32x4 acc = {0.f, 0.f, 0.f, 0.f};
#pragma unroll
    for (int kf = 0; kf < 8; ++kf) {
      const half8 av = *(const half8*)(pk + (size_t)((wv * 8 + kf) * 64 + lane) * 8);
      acc = __builtin_amdgcn_mfma_f32_16x16x32_f16(av, sf[kf], acc, 0, 0, 0);
    }
    const int o0 = wv * 16 + quad * 4;
    half4 h;
#pragma unroll
    for (int r = 0; r < 4; ++r) { const float z = acc[r]; h[r] = (_Float16)(z / (1.f + __expf(-z))); }
    *(half4*)(Hs1 + col * HSP + o0) = h;
  }
#pragma unroll
  for (int t = 0; t < 4; ++t) {
    const int mt = wv * 4 + t;
    f32x4 acc = {0.f, 0.f, 0.f, 0.f};
#pragma unroll
    for (int kf = 0; kf < 8; ++kf) {
      const half8 av = *(const half8*)(pk + 16384 + (size_t)((mt * 8 + kf) * 64 + lane) * 8);
      acc = __builtin_amdgcn_mfma_f32_16x16x32_f16(av, sf[kf], acc, 0, 0, 0);
    }
    const int o0 = mt * 16 + quad * 4;
    half4 g;
#pragma unroll
    for (int r = 0; r < 4; ++r) g[r] = (_Float16)(1.f / (1.f + __expf(-acc[r])));
    *(half4*)(G1v + col * GP + o0) = g;
  }
}

// W1: scalar L2 (K=64). Same tile distribution.
__device__ __forceinline__ void scal_mid(const _Float16* HsIn,
    const _Float16* __restrict__ pkS, const _Float16* __restrict__ pkG,
    _Float16* HsOut, _Float16* Gv)
{
  const int lane = threadIdx.x & 63;
  const int wv   = threadIdx.x >> 6;
  const int col  = lane & 15;
  const int quad = lane >> 4;
  half8 bf[2];
#pragma unroll
  for (int kf = 0; kf < 2; ++kf)
    bf[kf] = *(const half8*)(HsIn + col * HSP + kf * 32 + quad * 8);
  {
    f32x4 acc = {0.f, 0.f, 0.f, 0.f};
#pragma unroll
    for (int kf = 0; kf < 2; ++kf) {
      const half8 av = *(const half8*)(pkS + (size_t)((wv * 2 + kf) * 64 + lane) * 8);
      acc = __builtin_amdgcn_mfma_f32_16x16x32_f16(av, bf[kf], acc, 0, 0, 0);
    }
    const int o0 = wv * 16 + quad * 4;
    half4 h;
#pragma unroll
    for (int r = 0; r < 4; ++r) { const float z = acc[r]; h[r] = (_Float16)(z / (1.f + __expf(-z))); }
    *(half4*)(HsOut + col * HSP + o0) = h;
  }
#pragma unroll
  for (int t = 0; t < 4; ++t) {
    const int mt = wv * 4 + t;
    f32x4 acc = {0.f, 0.f, 0.f, 0.f};
#pragma unroll
    for (int kf = 0; kf < 2; ++kf) {
      const half8 av = *(const half8*)(pkG + (size_t)((mt * 2 + kf) * 64 + lane) * 8);
      acc = __builtin_amdgcn_mfma_f32_16x16x32_f16(av, bf[kf], acc, 0, 0, 0);
    }
    const int o0 = mt * 16 + quad * 4;
    half4 g;
#pragma unroll
    for (int r = 0; r < 4; ++r) g[r] = (_Float16)(1.f / (1.f + __expf(-acc[r])));
    *(half4*)(Gv + col * GP + o0) = g;
  }
}

// W2: scalar L3: wave0 does silu tiles + folded w4 dot; waves 1-3 do G3.
__device__ __forceinline__ void scal_last(const _Float16* Hs2,
    const _Float16* __restrict__ pkS, const _Float16* __restrict__ pkG,
    _Float16* G3v, const float* __restrict__ w4, float* __restrict__ out, int b0)
{
  const int lane = threadIdx.x & 63;
  const int wv   = threadIdx.x >> 6;
  const int col  = lane & 15;
  const int quad = lane >> 4;
  half8 bf[2];
#pragma unroll
  for (int kf = 0; kf < 2; ++kf)
    bf[kf] = *(const half8*)(Hs2 + col * HSP + kf * 32 + quad * 8);
  if (wv == 0) {
    float s = 0.f;
#pragma unroll
    for (int mt = 0; mt < 4; ++mt) {
      f32x4 acc = {0.f, 0.f, 0.f, 0.f};
#pragma unroll
      for (int kf = 0; kf < 2; ++kf) {
        const half8 av = *(const half8*)(pkS + (size_t)((mt * 2 + kf) * 64 + lane) * 8);
        acc = __builtin_amdgcn_mfma_f32_16x16x32_f16(av, bf[kf], acc, 0, 0, 0);
      }
      const int o0 = mt * 16 + quad * 4;
#pragma unroll
      for (int r = 0; r < 4; ++r) {
        const float z = acc[r];
        s += (z / (1.f + __expf(-z))) * w4[o0 + r];
      }
    }
    s += __shfl_xor(s, 16, 64);
    s += __shfl_xor(s, 32, 64);
    if (quad == 0) out[(size_t)(b0 + col) * OUT_COLS] = s * 0.125f;
  } else {
    const int t0 = (wv == 1) ? 0 : (wv == 2) ? 6 : 11;
    const int tn = (wv == 1) ? 6 : 5;
    for (int t = 0; t < tn; ++t) {
      const int mt = t0 + t;
      f32x4 acc = {0.f, 0.f, 0.f, 0.f};
#pragma unroll
      for (int kf = 0; kf < 2; ++kf) {
        const half8 av = *(const half8*)(pkG + (size_t)((mt * 2 + kf) * 64 + lane) * 8);
        acc = __builtin_amdgcn_mfma_f32_16x16x32_f16(av, bf[kf], acc, 0, 0, 0);
      }
      const int o0 = mt * 16 + quad * 4;
      half4 g;
#pragma unroll
      for (int r = 0; r < 4; ++r) g[r] = (_Float16)(1.f / (1.f + __expf(-acc[r])));
      *(half4*)(G3v + col * GP + o0) = g;
    }
  }
}

// ---------------------------------------------------------------------------
// Main kernel.
// ---------------------------------------------------------------------------
__global__ __launch_bounds__(256, 2) void fused_decoder(
    const float* __restrict__ vraw, const float* __restrict__ w4,
    const _Float16* __restrict__ pk, float* __restrict__ out)
{
  __shared__ __align__(16) _Float16 smem[SMEM_ELTS];
  _Float16* G1  = smem + OFF_G1;
  _Float16* G2  = smem + OFF_G2;
  _Float16* G3  = smem + OFF_G3;
  _Float16* Hs1 = smem + OFF_HS1;
  _Float16* Hs2 = smem + OFF_HS2;
  const int wv = threadIdx.x >> 6;
  _Float16* HSa = smem + OFF_SCR + wv * 2304;
  _Float16* HSb = HSa + 1152;
  const int b0 = blockIdx.x * B_ROWS;

  half8 sf[8];
  load_scal_frags(vraw, b0, sf);
  scal_L1(sf, pk, Hs1, G1);
  __syncthreads();
  scal_mid(Hs1, pk + P2BASE, pk + P2BASE + 4096, Hs2, G2);
  __syncthreads();
  scal_last(Hs2, pk + P3BASE, pk + P3BASE + 4096, G3, w4, out, b0);
  __syncthreads();

  // phase 2: cost-balanced static wave assignment (no barriers).
  if (wv == 0) {
    run_chain<2, 0, 5>(vraw, pk, G1, G2, G3, HSa, HSb, w4, out, b0);
    run_chain<3, 0, 4>(vraw, pk, G1, G2, G3, HSa, HSb, w4, out, b0);
  } else if (wv == 1) {
    run_chain<1, 0, 3>(vraw, pk, G1, G2, G3, HSa, HSb, w4, out, b0);
    run_chain<3, 4, 3>(vraw, pk, G1, G2, G3, HSa, HSb, w4, out, b0);
    run_chain<4, 0, 5>(vraw, pk, G1, G2, G3, HSa, HSb, w4, out, b0);
  } else if (wv == 2) {
    run_chain<6, 0, 13>(vraw, pk, G1, G2, G3, HSa, HSb, w4, out, b0);
    run_chain<4, 5, 1>(vraw, pk, G1, G2, G3, HSa, HSb, w4, out, b0);
  } else {
    run_chain<5, 0, 11>(vraw, pk, G1, G2, G3, HSa, HSb, w4, out, b0);
    run_chain<4, 6, 3>(vraw, pk, G1, G2, G3, HSa, HSb, w4, out, b0);
  }
}

extern "C" void kernel_launch(void* const* d_in, const int* in_sizes, int n_in,
                              void* d_out, int out_size, void* d_ws, size_t ws_size,
                              hipStream_t stream)
{
  (void)in_sizes; (void)n_in; (void)out_size; (void)ws_size;
  const float* vraw = (const float*)d_in[0];
  const float* w1   = (const float*)d_in[1];
  const float* w2   = (const float*)d_in[2];
  const float* w3   = (const float*)d_in[3];
  const float* w4   = (const float*)d_in[4];
  float* out = (float*)d_out;
  _Float16* packed = (_Float16*)d_ws;   // 172032 elems = 344064 B

  prep_weights<<<84, 256, 0, stream>>>(w1, w2, w3, packed);
  fused_decoder<<<16384 / B_ROWS, 256, 0, stream>>>(vraw, w4, packed, out);
}